// Round 2
// baseline (1988.594 us; speedup 1.0000x reference)
//
#include <hip/hip_runtime.h>
#include <hip/hip_fp16.h>

typedef _Float16 half8 __attribute__((ext_vector_type(8)));
typedef float floatx4 __attribute__((ext_vector_type(4)));

// d_ws half-element layout (packed fragment-major, hi then lo per layer)
#define W1H_OFF 0
#define W1L_OFF 32768
#define W2H_OFF 65536
#define W2L_OFF 131072
#define W3H_OFF 196608
#define W3L_OFF 212992

__device__ __forceinline__ floatx4 mfma16(half8 a, half8 b, floatx4 c) {
    return __builtin_amdgcn_mfma_f32_16x16x32_f16(a, b, c, 0, 0, 0);
}

// Tsitouras 5(4): row s gives coefficients for combine after eval s
__device__ const float dCoef[6][6] = {
    {0.161f, 0.f, 0.f, 0.f, 0.f, 0.f},
    {-0.008480655492356989f, 0.335480655492357f, 0.f, 0.f, 0.f, 0.f},
    {2.8971530571054935f, -6.359448489975075f, 4.3622954328695815f, 0.f, 0.f, 0.f},
    {5.325864828439257f, -11.748883564062828f, 7.4955393428898365f, -0.09249506636175525f, 0.f, 0.f},
    {5.86145544294642f, -12.92096931784711f, 8.159367898576159f, -0.071584973281401f, -0.028269050394068383f, 0.f},
    {0.09646076681806523f, 0.01f, 0.4798896504144996f, 1.379008574103742f, -3.290069515436081f, 2.324710524099774f},
};

// Pack W[n][k] (row-major [N][K] fp32) into MFMA-B fragment-major fp16 hi/lo
__global__ __launch_bounds__(256) void pack_weights(
    const float* __restrict__ W1, const float* __restrict__ W2,
    const float* __restrict__ W3, _Float16* __restrict__ ws)
{
    int e = blockIdx.x * 256 + threadIdx.x;  // 0..114687
    const float* W;
    int K, NT, hoff, loff, eb = e;
    if (e < 32768)      { W = W1; K = 128; NT = 16; hoff = W1H_OFF; loff = W1L_OFF; }
    else if (e < 98304) { W = W2; K = 256; NT = 16; hoff = W2H_OFF; loff = W2L_OFF; eb = e - 32768; }
    else                { W = W3; K = 256; NT = 4;  hoff = W3H_OFF; loff = W3L_OFF; eb = e - 98304; }
    int j = eb & 7, l = (eb >> 3) & 63, t = eb >> 9;
    int tn = t % NT, kk = t / NT;
    int n = tn * 16 + (l & 15);
    int k = kk * 32 + ((l >> 4) * 8) + j;
    float wv = W[n * K + k];
    _Float16 hi = (_Float16)wv;
    _Float16 lo = (_Float16)(wv - (float)hi);
    ws[hoff + eb] = hi;
    ws[loff + eb] = lo;
}

// swizzled LDS activation fragment read: element idx = (row*K + k0) ^ ((row&7)<<3)
__device__ __forceinline__ half8 lds_frag(const _Float16* s, int K, int row, int k0) {
    int idx = (row * K + k0) ^ ((row & 7) << 3);
    return *reinterpret_cast<const half8*>(s + idx);
}

__global__ __launch_bounds__(512, 2) void ode_kernel(
    const float* __restrict__ x0, const float* __restrict__ u,
    const float* __restrict__ b1, const float* __restrict__ b2,
    const float* __restrict__ b3, const _Float16* __restrict__ ws,
    const int* __restrict__ t0p, const int* __restrict__ t1p,
    float* __restrict__ out)
{
    __shared__ _Float16 sW1h[32768];           // 64 KB: W1-hi packed fragment-major
    __shared__ _Float16 sW3h[16384];           // 32 KB: W3-hi packed
    __shared__ _Float16 sA1h[4096], sA1l[4096];
    __shared__ _Float16 sA2h[4096], sA2l[4096];
    __shared__ _Float16 sZh[2048], sZl[2048];
    __shared__ float sKf[5 * 1024];            // k1..k5 in C-frag positions
    // total LDS = 65536+32768+16384+16384+8192+20480 = 159744 B

    const int tid = threadIdx.x;
    const int lane = tid & 63;
    const int w = tid >> 6;           // wave 0..7
    const int w3 = w & 3;
    const int r0 = blockIdx.x * 16;

    // ---- stage W1-hi / W3-hi into LDS ----
    {
        const half8* s1 = reinterpret_cast<const half8*>(ws + W1H_OFF);
        half8* d1 = reinterpret_cast<half8*>(sW1h);
        #pragma unroll
        for (int i = 0; i < 8; ++i) d1[tid + 512 * i] = s1[tid + 512 * i];
        const half8* s3 = reinterpret_cast<const half8*>(ws + W3H_OFF);
        half8* d3 = reinterpret_cast<half8*>(sW3h);
        #pragma unroll
        for (int i = 0; i < 4; ++i) d3[tid + 512 * i] = s3[tid + 512 * i];
    }
    // ---- register-resident weights ----
    half8 rW2h[2][8], rW2l[2][8], rW1l[2][4], rW3l[8];
    {
        const half8* g2h = reinterpret_cast<const half8*>(ws + W2H_OFF);
        const half8* g2l = reinterpret_cast<const half8*>(ws + W2L_OFF);
        const half8* g1l = reinterpret_cast<const half8*>(ws + W1L_OFF);
        const half8* g3l = reinterpret_cast<const half8*>(ws + W3L_OFF);
        #pragma unroll
        for (int t = 0; t < 2; ++t)
            #pragma unroll
            for (int kk = 0; kk < 8; ++kk) {
                rW2h[t][kk] = g2h[(kk * 16 + 2 * w + t) * 64 + lane];
                rW2l[t][kk] = g2l[(kk * 16 + 2 * w + t) * 64 + lane];
            }
        #pragma unroll
        for (int t = 0; t < 2; ++t)
            #pragma unroll
            for (int kk = 0; kk < 4; ++kk)
                rW1l[t][kk] = g1l[(kk * 16 + 2 * w + t) * 64 + lane];
        #pragma unroll
        for (int kk = 0; kk < 8; ++kk)
            rW3l[kk] = g3l[(kk * 4 + w3) * 64 + lane];
    }
    float rB1[2], rB2[2], rB3;
    rB1[0] = b1[(lane & 15) + (2 * w) * 16];
    rB1[1] = b1[(lane & 15) + (2 * w + 1) * 16];
    rB2[0] = b2[(lane & 15) + (2 * w) * 16];
    rB2[1] = b2[(lane & 15) + (2 * w + 1) * 16];
    rB3 = b3[(lane & 15) + 16 * w3];

    const int q4 = (lane >> 4) * 4;
    const int ocol = (lane & 15) + 16 * w3;   // L3 C-frag col (valid on w<4)

    // y state in C-frag registers (used on w<4; loaded on all waves harmlessly)
    float yv[4];
    #pragma unroll
    for (int r = 0; r < 4; ++r)
        yv[r] = x0[(r0 + q4 + r) * 64 + ocol];

    // Z init (all 512 threads): z = y0 | u, fp16 hi/lo, swizzled
    {
        int row = tid >> 5, c0 = (tid & 31) * 2;
        float y0v = x0[(r0 + row) * 64 + c0], y1v = x0[(r0 + row) * 64 + c0 + 1];
        float u0v = u[(r0 + row) * 64 + c0], u1v = u[(r0 + row) * 64 + c0 + 1];
        int zy = (row * 128 + c0) ^ ((row & 7) << 3);
        int zu = (row * 128 + 64 + c0) ^ ((row & 7) << 3);
        _Float16 h0 = (_Float16)y0v, h1 = (_Float16)y1v;
        sZh[zy] = h0; sZh[zy + 1] = h1;
        sZl[zy] = (_Float16)(y0v - (float)h0);
        sZl[zy + 1] = (_Float16)(y1v - (float)h1);
        _Float16 g0 = (_Float16)u0v, g1 = (_Float16)u1v;
        sZh[zu] = g0; sZh[zu + 1] = g1;
        sZl[zu] = (_Float16)(u0v - (float)g0);
        sZl[zu + 1] = (_Float16)(u1v - (float)g1);
    }
    __syncthreads();

    const int nsteps = (t1p[0] - t0p[0]) * 60;  // h = 60s = 1/60 hr
    const float H = 1.0f / 60.0f;
    const int arow = lane & 15;
    const int kb = (lane >> 4) * 8;

    #pragma unroll 1
    for (int step = 0; step < nsteps; ++step) {
        #pragma unroll 1
        for (int stg = 0; stg < 6; ++stg) {
            // ---------- Layer 1: z[16x128] @ W1^T -> relu -> sA1 ----------
            {
                floatx4 acc[2][2];
                #pragma unroll
                for (int t = 0; t < 2; ++t) {
                    acc[t][0] = floatx4{rB1[t], rB1[t], rB1[t], rB1[t]};
                    acc[t][1] = floatx4{0.f, 0.f, 0.f, 0.f};
                }
                #pragma unroll
                for (int kk = 0; kk < 4; ++kk) {
                    half8 ah = lds_frag(sZh, 128, arow, kb + kk * 32);
                    half8 al = lds_frag(sZl, 128, arow, kb + kk * 32);
                    #pragma unroll
                    for (int t = 0; t < 2; ++t) {
                        half8 bh = *reinterpret_cast<const half8*>(
                            sW1h + ((kk * 16 + 2 * w + t) * 64 + lane) * 8);
                        acc[t][kk & 1] = mfma16(ah, bh, acc[t][kk & 1]);
                        acc[t][kk & 1] = mfma16(ah, rW1l[t][kk], acc[t][kk & 1]);
                        acc[t][kk & 1] = mfma16(al, bh, acc[t][kk & 1]);
                    }
                }
                #pragma unroll
                for (int t = 0; t < 2; ++t) {
                    int col = (lane & 15) + (2 * w + t) * 16;
                    #pragma unroll
                    for (int r = 0; r < 4; ++r) {
                        int orow = q4 + r;
                        float v = fmaxf(acc[t][0][r] + acc[t][1][r], 0.f);
                        _Float16 hi = (_Float16)v, lo = (_Float16)(v - (float)hi);
                        int idx = (orow * 256 + col) ^ ((orow & 7) << 3);
                        sA1h[idx] = hi;
                        sA1l[idx] = lo;
                    }
                }
            }
            __syncthreads();
            // ---------- Layer 2: a1[16x256] @ W2^T -> relu -> sA2 (W2 in regs) ----------
            {
                floatx4 acc[2][2];
                #pragma unroll
                for (int t = 0; t < 2; ++t) {
                    acc[t][0] = floatx4{rB2[t], rB2[t], rB2[t], rB2[t]};
                    acc[t][1] = floatx4{0.f, 0.f, 0.f, 0.f};
                }
                #pragma unroll
                for (int kk = 0; kk < 8; ++kk) {
                    half8 ah = lds_frag(sA1h, 256, arow, kb + kk * 32);
                    half8 al = lds_frag(sA1l, 256, arow, kb + kk * 32);
                    #pragma unroll
                    for (int t = 0; t < 2; ++t) {
                        acc[t][kk & 1] = mfma16(ah, rW2h[t][kk], acc[t][kk & 1]);
                        acc[t][kk & 1] = mfma16(ah, rW2l[t][kk], acc[t][kk & 1]);
                        acc[t][kk & 1] = mfma16(al, rW2h[t][kk], acc[t][kk & 1]);
                    }
                }
                #pragma unroll
                for (int t = 0; t < 2; ++t) {
                    int col = (lane & 15) + (2 * w + t) * 16;
                    #pragma unroll
                    for (int r = 0; r < 4; ++r) {
                        int orow = q4 + r;
                        float v = fmaxf(acc[t][0][r] + acc[t][1][r], 0.f);
                        _Float16 hi = (_Float16)v, lo = (_Float16)(v - (float)hi);
                        int idx = (orow * 256 + col) ^ ((orow & 7) << 3);
                        sA2h[idx] = hi;
                        sA2l[idx] = lo;
                    }
                }
            }
            __syncthreads();
            // ---------- Layer 3 + RK combine (waves 0-3) ----------
            if (w < 4) {
                floatx4 aE = floatx4{rB3, rB3, rB3, rB3};
                floatx4 aO = floatx4{0.f, 0.f, 0.f, 0.f};
                #pragma unroll
                for (int kk = 0; kk < 8; ++kk) {
                    half8 ah = lds_frag(sA2h, 256, arow, kb + kk * 32);
                    half8 al = lds_frag(sA2l, 256, arow, kb + kk * 32);
                    half8 bh = *reinterpret_cast<const half8*>(
                        sW3h + ((kk * 4 + w) * 64 + lane) * 8);
                    if (kk & 1) {
                        aO = mfma16(ah, bh, aO);
                        aO = mfma16(ah, rW3l[kk], aO);
                        aO = mfma16(al, bh, aO);
                    } else {
                        aE = mfma16(ah, bh, aE);
                        aE = mfma16(ah, rW3l[kk], aE);
                        aE = mfma16(al, bh, aE);
                    }
                }
                // combine: z = y + H * (sum_{j<stg} c_j*k_j + c_stg*k_new)
                #pragma unroll
                for (int r = 0; r < 4; ++r) {
                    int orow = q4 + r;
                    float kc = aE[r] + aO[r];
                    float s = dCoef[stg][stg] * kc;
                    for (int j = 0; j < stg; ++j)
                        s += dCoef[stg][j] * sKf[j * 1024 + orow * 64 + ocol];
                    float z = yv[r] + H * s;
                    if (stg < 5) sKf[stg * 1024 + orow * 64 + ocol] = kc;
                    else yv[r] = z;  // final combine of the step
                    int idx = (orow * 128 + ocol) ^ ((orow & 7) << 3);
                    _Float16 h0 = (_Float16)z;
                    sZh[idx] = h0;
                    sZl[idx] = (_Float16)(z - (float)h0);
                }
            }
            __syncthreads();
        }
    }
    // ---- write y_final from registers ----
    if (w < 4) {
        #pragma unroll
        for (int r = 0; r < 4; ++r)
            out[(r0 + q4 + r) * 64 + ocol] = yv[r];
    }
}

extern "C" void kernel_launch(void* const* d_in, const int* in_sizes, int n_in,
                              void* d_out, int out_size, void* d_ws, size_t ws_size,
                              hipStream_t stream)
{
    const float* x0 = (const float*)d_in[0];
    const float* u  = (const float*)d_in[1];
    const float* W1 = (const float*)d_in[2];
    const float* b1 = (const float*)d_in[3];
    const float* W2 = (const float*)d_in[4];
    const float* b2 = (const float*)d_in[5];
    const float* W3 = (const float*)d_in[6];
    const float* b3 = (const float*)d_in[7];
    const int* t0 = (const int*)d_in[8];
    const int* t1 = (const int*)d_in[9];
    float* out = (float*)d_out;
    _Float16* ws = (_Float16*)d_ws;

    pack_weights<<<448, 256, 0, stream>>>(W1, W2, W3, ws);
    ode_kernel<<<64, 512, 0, stream>>>(x0, u, b1, b2, b3, ws, t0, t1, out);
}